// Round 12
// baseline (182.382 us; speedup 1.0000x reference)
//
#include <hip/hip_runtime.h>
#include <hip/hip_bf16.h>

#define NB 64    // batch
#define NT 128   // tokens (seq)
#define NE 4     // experts
#define ND 128   // model dim
#define NK 512   // ffn hidden dim
#define MH 16    // batch rows per block (quarter)

typedef __attribute__((ext_vector_type(8))) short bf16x8;
typedef __attribute__((ext_vector_type(4))) float f32x4;

__device__ __forceinline__ short f2bf(float f) {
    union { __hip_bfloat16 b; short s; } u;
    u.b = __float2bfloat16(f);
    return u.s;
}

__device__ __forceinline__ bf16x8 cvt8(const float* f) {
    bf16x8 r;
    #pragma unroll
    for (int j = 0; j < 8; ++j) r[j] = f2bf(f[j]);
    return r;
}

__device__ __forceinline__ float gelu_erf(float x) {
    return 0.5f * x * (1.0f + erff(x * 0.70710678118654752f));
}

// ---------------- router: one wave per token (4 tokens per wave via loop) ----
__global__ __launch_bounds__(256)
void moe_gates(const float* __restrict__ x,
               const float* __restrict__ rw,
               const float* __restrict__ rb,
               float* __restrict__ gates_ws,
               float* __restrict__ aux_partial)
{
    const int tid  = threadIdx.x;
    const int lane = tid & 63;
    const int wave = tid >> 6;
    __shared__ float waux[4];

    const float4 rw0 = *(const float4*)(rw + lane * 4);
    const float4 rw1 = *(const float4*)(rw + (64 + lane) * 4);
    const float4 rbv = *(const float4*)rb;

    float aux = 0.f;
    #pragma unroll
    for (int i = 0; i < 4; ++i) {
        const int tok = (blockIdx.x * 4 + wave) * 4 + i;       // b*NT + t
        const float x0 = x[tok * ND + lane];
        const float x1 = x[tok * ND + 64 + lane];
        float p0 = x0 * rw0.x + x1 * rw1.x;
        float p1 = x0 * rw0.y + x1 * rw1.y;
        float p2 = x0 * rw0.z + x1 * rw1.z;
        float p3 = x0 * rw0.w + x1 * rw1.w;
        #pragma unroll
        for (int off = 32; off > 0; off >>= 1) {
            p0 += __shfl_xor(p0, off);
            p1 += __shfl_xor(p1, off);
            p2 += __shfl_xor(p2, off);
            p3 += __shfl_xor(p3, off);
        }
        if (lane == 0) {
            p0 = fmaxf(p0 + rbv.x, 0.f);
            p1 = fmaxf(p1 + rbv.y, 0.f);
            p2 = fmaxf(p2 + rbv.z, 0.f);
            p3 = fmaxf(p3 + rbv.w, 0.f);
            const float s   = p0 + p1 + p2 + p3;
            const float inv = 1.f / (s + 1e-9f);
            float4 g; g.x = p0 * inv; g.y = p1 * inv; g.z = p2 * inv; g.w = p3 * inv;
            *(float4*)(gates_ws + tok * NE) = g;
            aux += s * inv;
        }
    }
    if (lane == 0) waux[wave] = aux;
    __syncthreads();
    if (tid == 0)
        aux_partial[blockIdx.x] = waux[0] + waux[1] + waux[2] + waux[3];
}

// ---------------- main: one block per (t, e, batch-quarter); 4 waves ---------
// M=16 + depth-4 consume-first ring (48 VGPR, proven 3.55 TB/s aggregate in
// R11). Fix vs R11: quarter-twins at {s, s+512, s+1024, s+1536} -> same
// bid%8 -> SAME XCD -> weight bytes fill that XCD's L2 once (R2-proven).
// launch_bounds(256,8): 8 blocks/CU -> full 2048-block co-residency.
__global__ __launch_bounds__(256, 8)
void moe_main(const float* __restrict__ x,
              const float* __restrict__ w1,
              const float* __restrict__ b1,
              const float* __restrict__ w2,
              const float* __restrict__ b2,
              const float* __restrict__ gates_ws,
              float* __restrict__ ws)
{
    const int bid  = blockIdx.x;
    const int h    = bid >> 9;          // batch quarter; twins same XCD (mod 8)
    const int s    = bid & 511;         // (t,e)
    const int t    = s >> 2;
    const int e    = s & 3;
    const int tid  = threadIdx.x;
    const int lane = tid & 63;
    const int wave = tid >> 6;
    const int l15  = lane & 15;
    const int l4   = lane >> 4;

    __shared__ short Hs[MH][NK + 8];    // 16 x 520 bf16 bits = 16,640 B
    __shared__ float gate_s[MH];

    if (tid < MH)
        gate_s[tid] = gates_ws[((h * MH + tid) * NT + t) * NE + e];

    // ---------------- GEMM1: X[16x128] * W1[128x512]; wave owns 128 cols -----
    const float* W1 = w1 + (size_t)((t * NE + e) * ND) * NK;  // [128 d][512 n]
    const float* B1 = b1 + (t * NE + e) * NK;
    const int n0 = wave * 128;

    // hoist the x fragments (1 m-frag x 4 ks)
    bf16x8 afr[4];
    {
        float xa[4][8];
        #pragma unroll
        for (int ks = 0; ks < 4; ++ks) {
            const float* xp = x + (size_t)((h * MH + l15) * NT + t) * ND + ks * 32 + l4 * 8;
            *(float4*)&xa[ks][0] = *(const float4*)(xp);
            *(float4*)&xa[ks][4] = *(const float4*)(xp + 4);
        }
        #pragma unroll
        for (int ks = 0; ks < 4; ++ks) afr[ks] = cvt8(xa[ks]);
    }

    f32x4 acc[8];
    #pragma unroll
    for (int n = 0; n < 8; ++n) acc[n] = (f32x4){0.f, 0.f, 0.f, 0.f};

    {
        const float* wbase = W1 + (size_t)(l4 * 8) * NK + n0 + l15;
        float wbuf[4][8];
        // prologue: p = 0..3  (ks=0, nt=p)
        #pragma unroll
        for (int q = 0; q < 4; ++q) {
            const float* wp = wbase + q * 16;
            #pragma unroll
            for (int j = 0; j < 8; ++j) wbuf[q][j] = wp[(size_t)j * NK];
        }

        #pragma unroll
        for (int p = 0; p < 32; ++p) {
            const int ks = p >> 3, nt = p & 7;
            // consume slot p&3 first...
            const bf16x8 bfr = cvt8(wbuf[p & 3]);
            // ...then refill the dead slot with iteration p+4's weights
            if (p < 28) {
                const int p4 = p + 4;
                const int ks4 = p4 >> 3, nt4 = p4 & 7;
                const float* wp = wbase + (size_t)(ks4 * 32) * NK + nt4 * 16;
                #pragma unroll
                for (int j = 0; j < 8; ++j) wbuf[p4 & 3][j] = wp[(size_t)j * NK];
            }
            acc[nt] = __builtin_amdgcn_mfma_f32_16x16x32_bf16(afr[ks], bfr, acc[nt], 0, 0, 0);
        }
    }

    // bias + exact-erf gelu -> bf16 H in LDS
    #pragma unroll
    for (int nt = 0; nt < 8; ++nt) {
        const int n = n0 + nt * 16 + l15;
        const float bb = B1[n];
        #pragma unroll
        for (int r = 0; r < 4; ++r) {
            const float hh = acc[nt][r] + bb;
            Hs[l4 * 4 + r][n] = f2bf(gelu_erf(hh));
        }
    }
    __syncthreads();

    // ---------------- GEMM2: H[16x512] * W2[512x128]; wave owns 32 cols ------
    const float* W2 = w2 + (size_t)((t * NE + e) * NK) * ND;  // [512 k][128 c]
    const float* B2 = b2 + (t * NE + e) * ND;
    const int c0 = wave * 32;

    f32x4 acc2[2];
    #pragma unroll
    for (int n = 0; n < 2; ++n) acc2[n] = (f32x4){0.f, 0.f, 0.f, 0.f};

    {
        const float* w2base = W2 + (size_t)(l4 * 8) * ND + c0 + l15;
        float wb2[4][8];
        // prologue: p = 0..3  (ks=0,1; nt=0,1)
        #pragma unroll
        for (int q = 0; q < 4; ++q) {
            const int ksq = q >> 1, ntq = q & 1;
            const float* wp = w2base + (size_t)(ksq * 32) * ND + ntq * 16;
            #pragma unroll
            for (int j = 0; j < 8; ++j) wb2[q][j] = wp[(size_t)j * ND];
        }

        bf16x8 a2;
        #pragma unroll
        for (int p = 0; p < 32; ++p) {
            const int ks = p >> 1, nt = p & 1;
            if (nt == 0)
                a2 = *(const bf16x8*)&Hs[l15][ks * 32 + l4 * 8];
            // consume slot p&3 first...
            const bf16x8 bfr = cvt8(wb2[p & 3]);
            // ...then refill the dead slot with iteration p+4's weights
            if (p < 28) {
                const int p4 = p + 4;
                const int ks4 = p4 >> 1, nt4 = p4 & 1;
                const float* wp = w2base + (size_t)(ks4 * 32) * ND + nt4 * 16;
                #pragma unroll
                for (int j = 0; j < 8; ++j) wb2[p4 & 3][j] = wp[(size_t)j * ND];
            }
            acc2[nt] = __builtin_amdgcn_mfma_f32_16x16x32_bf16(a2, bfr, acc2[nt], 0, 0, 0);
        }
    }

    // gate-weighted epilogue -> ws[e][b][t][d]
    #pragma unroll
    for (int nt = 0; nt < 2; ++nt) {
        const int c = c0 + nt * 16 + l15;
        const float bb = B2[c];
        #pragma unroll
        for (int r = 0; r < 4; ++r) {
            const int bl = l4 * 4 + r;
            const int b  = h * MH + bl;
            const float v = (acc2[nt][r] + bb) * gate_s[bl];
            ws[(size_t)(e * NB * NT + b * NT + t) * ND + c] = v;
        }
    }
}

// ---------------- reduce 4 expert contributions + finalize aux ---------------
__global__ __launch_bounds__(256)
void moe_reduce(const float* __restrict__ ws,
                const float* __restrict__ aux_partial,
                float* __restrict__ out)
{
    const int i = blockIdx.x * blockDim.x + threadIdx.x;
    const int stride = NB * NT * ND / 4;
    const float4* w = (const float4*)ws;
    const float4 a = w[i];
    const float4 b = w[i + stride];
    const float4 c = w[i + 2 * stride];
    const float4 d = w[i + 3 * stride];
    float4 r;
    r.x = a.x + b.x + c.x + d.x;
    r.y = a.y + b.y + c.y + d.y;
    r.z = a.z + b.z + c.z + d.z;
    r.w = a.w + b.w + c.w + d.w;
    ((float4*)out)[i] = r;

    if (blockIdx.x == 0) {
        const int tid = threadIdx.x;
        float s = aux_partial[tid] + aux_partial[tid + 256];
        #pragma unroll
        for (int off = 32; off > 0; off >>= 1) s += __shfl_xor(s, off);
        __shared__ float wsum[4];
        if ((tid & 63) == 0) wsum[tid >> 6] = s;
        __syncthreads();
        if (tid == 0)
            out[NB * NT * ND] = (wsum[0] + wsum[1] + wsum[2] + wsum[3]) *
                                (0.01f / (NB * NT));
    }
}

// ---------------- fallback (ws too small): self-contained, atomics -----------
__global__ __launch_bounds__(256, 2)
void moe_main_fb(const float* __restrict__ x,
                 const float* __restrict__ w1,
                 const float* __restrict__ b1,
                 const float* __restrict__ w2,
                 const float* __restrict__ b2,
                 const float* __restrict__ rw,
                 const float* __restrict__ rb,
                 float* __restrict__ out)
{
    const int blk  = blockIdx.x;
    const int t    = blk >> 2;
    const int e    = blk & 3;
    const int tid  = threadIdx.x;
    const int lane = tid & 63;
    const int wave = tid >> 6;
    const int l15  = lane & 15;
    const int l4   = lane >> 4;

    __shared__ short Hs[NB][NK + 8];
    __shared__ float gate_s[NB];

    if (tid < NB) {
        const int b = tid;
        const float* xr = x + (b * NT + t) * ND;
        float l0 = rb[0], l1 = rb[1], l2 = rb[2], l3 = rb[3];
        #pragma unroll 8
        for (int d = 0; d < ND; ++d) {
            const float xv = xr[d];
            const float* w = rw + d * NE;
            l0 += xv * w[0]; l1 += xv * w[1]; l2 += xv * w[2]; l3 += xv * w[3];
        }
        l0 = fmaxf(l0, 0.f); l1 = fmaxf(l1, 0.f); l2 = fmaxf(l2, 0.f); l3 = fmaxf(l3, 0.f);
        const float ss  = l0 + l1 + l2 + l3;
        const float inv = 1.f / (ss + 1e-9f);
        const float ge  = (e == 0) ? l0 : (e == 1) ? l1 : (e == 2) ? l2 : l3;
        gate_s[b] = ge * inv;
        if (e == 0) {
            float aux = ss * inv;
            #pragma unroll
            for (int off = 32; off > 0; off >>= 1) aux += __shfl_down(aux, off);
            if (lane == 0) atomicAdd(out + NB * NT * ND, aux * (0.01f / (NB * NT)));
        }
    }
    __syncthreads();

    const float* W1 = w1 + (size_t)((t * NE + e) * ND) * NK;
    const float* B1 = b1 + (t * NE + e) * NK;
    const int n0 = wave * 128;

    f32x4 acc[4][8];
    #pragma unroll
    for (int m = 0; m < 4; ++m)
        #pragma unroll
        for (int n = 0; n < 8; ++n) acc[m][n] = (f32x4){0.f, 0.f, 0.f, 0.f};

    #pragma unroll
    for (int ks = 0; ks < 4; ++ks) {
        const int d0 = ks * 32 + l4 * 8;
        bf16x8 afr[4];
        #pragma unroll
        for (int m = 0; m < 4; ++m) {
            const int b = m * 16 + l15;
            const float* xp = x + (b * NT + t) * ND + d0;
            float xf[8];
            *(float4*)&xf[0] = *(const float4*)(xp);
            *(float4*)&xf[4] = *(const float4*)(xp + 4);
            afr[m] = cvt8(xf);
        }
        #pragma unroll
        for (int nt = 0; nt < 8; ++nt) {
            const int n = n0 + nt * 16 + l15;
            const float* wp = W1 + (size_t)d0 * NK + n;
            float wf[8];
            #pragma unroll
            for (int j = 0; j < 8; ++j) wf[j] = wp[(size_t)j * NK];
            const bf16x8 bfr = cvt8(wf);
            #pragma unroll
            for (int m = 0; m < 4; ++m)
                acc[m][nt] = __builtin_amdgcn_mfma_f32_16x16x32_bf16(afr[m], bfr, acc[m][nt], 0, 0, 0);
        }
    }

    #pragma unroll
    for (int nt = 0; nt < 8; ++nt) {
        const int n = n0 + nt * 16 + l15;
        const float bb = B1[n];
        #pragma unroll
        for (int m = 0; m < 4; ++m) {
            const int row = m * 16 + l4 * 4;
            #pragma unroll
            for (int r = 0; r < 4; ++r) {
                const float hh = acc[m][nt][r] + bb;
                Hs[row + r][n] = f2bf(gelu_erf(hh));
            }
        }
    }
    __syncthreads();

    const float* W2 = w2 + (size_t)((t * NE + e) * NK) * ND;
    const float* B2 = b2 + (t * NE + e) * ND;
    const int c0 = wave * 32;

    f32x4 acc2[4][2];
    #pragma unroll
    for (int m = 0; m < 4; ++m)
        #pragma unroll
        for (int n = 0; n < 2; ++n) acc2[m][n] = (f32x4){0.f, 0.f, 0.f, 0.f};

    #pragma unroll 4
    for (int ks = 0; ks < 16; ++ks) {
        const int k0 = ks * 32 + l4 * 8;
        bf16x8 afr[4];
        #pragma unroll
        for (int m = 0; m < 4; ++m)
            afr[m] = *(const bf16x8*)(&Hs[m * 16 + l15][k0]);
        #pragma unroll
        for (int nt = 0; nt < 2; ++nt) {
            const int c = c0 + nt * 16 + l15;
            const float* wp = W2 + (size_t)k0 * ND + c;
            float wf[8];
            #pragma unroll
            for (int j = 0; j < 8; ++j) wf[j] = wp[(size_t)j * ND];
            const bf16x8 bfr = cvt8(wf);
            #pragma unroll
            for (int m = 0; m < 4; ++m)
                acc2[m][nt] = __builtin_amdgcn_mfma_f32_16x16x32_bf16(afr[m], bfr, acc2[m][nt], 0, 0, 0);
        }
    }

    #pragma unroll
    for (int nt = 0; nt < 2; ++nt) {
        const int c = c0 + nt * 16 + l15;
        const float bb = B2[c];
        #pragma unroll
        for (int m = 0; m < 4; ++m) {
            #pragma unroll
            for (int r = 0; r < 4; ++r) {
                const int b = m * 16 + l4 * 4 + r;
                const float v = (acc2[m][nt][r] + bb) * gate_s[b];
                atomicAdd(out + (size_t)(b * NT + t) * ND + c, v);
            }
        }
    }
}

extern "C" void kernel_launch(void* const* d_in, const int* in_sizes, int n_in,
                              void* d_out, int out_size, void* d_ws, size_t ws_size,
                              hipStream_t stream) {
    const float* x  = (const float*)d_in[0];
    const float* w1 = (const float*)d_in[1];
    const float* b1 = (const float*)d_in[2];
    const float* w2 = (const float*)d_in[3];
    const float* b2 = (const float*)d_in[4];
    const float* rw = (const float*)d_in[5];
    const float* rb = (const float*)d_in[6];
    float* out = (float*)d_out;

    const size_t contrib_elems = (size_t)NE * NB * NT * ND;           // 16 MiB
    const size_t gates_elems   = (size_t)NB * NT * NE;
    const size_t aux_elems     = 512;
    const size_t ws_need = (contrib_elems + gates_elems + aux_elems) * sizeof(float);

    if (ws_size >= ws_need) {
        float* contrib = (float*)d_ws;
        float* gates   = contrib + contrib_elems;
        float* auxp    = gates + gates_elems;

        moe_gates<<<512, 256, 0, stream>>>(x, rw, rb, gates, auxp);
        moe_main<<<NT * NE * 4, 256, 0, stream>>>(x, w1, b1, w2, b2, gates, contrib);
        moe_reduce<<<(NB * NT * ND / 4) / 256, 256, 0, stream>>>(contrib, auxp, out);
    } else {
        hipMemsetAsync(d_out, 0, (size_t)(NB * NT * ND + 1) * sizeof(float), stream);
        moe_main_fb<<<NT * NE, 256, 0, stream>>>(x, w1, b1, w2, b2, rw, rb, out);
    }
}

// Round 15
// 149.188 us; speedup vs baseline: 1.2225x; 1.2225x over previous
//
#include <hip/hip_runtime.h>
#include <hip/hip_bf16.h>

#define NB 64    // batch
#define NT 128   // tokens (seq)
#define NE 4     // experts
#define ND 128   // model dim
#define NK 512   // ffn hidden dim
#define MH 16    // batch rows per wave-quarter

typedef __attribute__((ext_vector_type(8))) short bf16x8;
typedef __attribute__((ext_vector_type(4))) float f32x4;

__device__ __forceinline__ short f2bf(float f) {
    union { __hip_bfloat16 b; short s; } u;
    u.b = __float2bfloat16(f);
    return u.s;
}

__device__ __forceinline__ bf16x8 cvt8(const float* f) {
    bf16x8 r;
    #pragma unroll
    for (int j = 0; j < 8; ++j) r[j] = f2bf(f[j]);
    return r;
}

__device__ __forceinline__ float gelu_erf(float x) {
    return 0.5f * x * (1.0f + erff(x * 0.70710678118654752f));
}

// ---------------- router: one wave per token (4 tokens per wave via loop) ----
__global__ __launch_bounds__(256)
void moe_gates(const float* __restrict__ x,
               const float* __restrict__ rw,
               const float* __restrict__ rb,
               float* __restrict__ gates_ws,
               float* __restrict__ aux_partial)
{
    const int tid  = threadIdx.x;
    const int lane = tid & 63;
    const int wave = tid >> 6;
    __shared__ float waux[4];

    const float4 rw0 = *(const float4*)(rw + lane * 4);
    const float4 rw1 = *(const float4*)(rw + (64 + lane) * 4);
    const float4 rbv = *(const float4*)rb;

    float aux = 0.f;
    #pragma unroll
    for (int i = 0; i < 4; ++i) {
        const int tok = (blockIdx.x * 4 + wave) * 4 + i;       // b*NT + t
        const float x0 = x[tok * ND + lane];
        const float x1 = x[tok * ND + 64 + lane];
        float p0 = x0 * rw0.x + x1 * rw1.x;
        float p1 = x0 * rw0.y + x1 * rw1.y;
        float p2 = x0 * rw0.z + x1 * rw1.z;
        float p3 = x0 * rw0.w + x1 * rw1.w;
        #pragma unroll
        for (int off = 32; off > 0; off >>= 1) {
            p0 += __shfl_xor(p0, off);
            p1 += __shfl_xor(p1, off);
            p2 += __shfl_xor(p2, off);
            p3 += __shfl_xor(p3, off);
        }
        if (lane == 0) {
            p0 = fmaxf(p0 + rbv.x, 0.f);
            p1 = fmaxf(p1 + rbv.y, 0.f);
            p2 = fmaxf(p2 + rbv.z, 0.f);
            p3 = fmaxf(p3 + rbv.w, 0.f);
            const float s   = p0 + p1 + p2 + p3;
            const float inv = 1.f / (s + 1e-9f);
            float4 g; g.x = p0 * inv; g.y = p1 * inv; g.z = p2 * inv; g.w = p3 * inv;
            *(float4*)(gates_ws + tok * NE) = g;
            aux += s * inv;
        }
    }
    if (lane == 0) waux[wave] = aux;
    __syncthreads();
    if (tid == 0)
        aux_partial[blockIdx.x] = waux[0] + waux[1] + waux[2] + waux[3];
}

// ---------------- main: ONE block per (t, e); 1024 threads = 16 waves --------
// Wave w = (h, wc): h = w>>2 batch-quarter (16 rows), wc = w&3 col-quarter.
// Each wave runs R11's proven structure (M=16, depth-4 consume-first ring,
// ~48 VGPR, high per-wave BW). Weight-read duplication exists ONLY within the
// block (4 waves share W1 cols / W2 cols) -> barrier-synced -> L1/L2 hits.
// Across blocks every weight byte is read once -> unique HBM fetch.
__global__ __launch_bounds__(1024, 8)
void moe_main(const float* __restrict__ x,
              const float* __restrict__ w1,
              const float* __restrict__ b1,
              const float* __restrict__ w2,
              const float* __restrict__ b2,
              const float* __restrict__ gates_ws,
              float* __restrict__ ws)
{
    const int bid  = blockIdx.x;        // (t,e)
    const int t    = bid >> 2;
    const int e    = bid & 3;
    const int tid  = threadIdx.x;
    const int lane = tid & 63;
    const int wave = tid >> 6;
    const int h    = wave >> 2;         // batch quarter (0..3)
    const int wc   = wave & 3;          // column quarter (0..3)
    const int l15  = lane & 15;
    const int l4   = lane >> 4;

    __shared__ short Hs[NB][NK + 8];    // 64 x 520 bf16 bits = 66,560 B
    __shared__ float gate_s[NB];

    if (tid < NB)
        gate_s[tid] = gates_ws[(tid * NT + t) * NE + e];

    // ---------------- GEMM1: X[16x128] * W1[128x512-slice]; 128 cols/wave ----
    const float* W1 = w1 + (size_t)((t * NE + e) * ND) * NK;  // [128 d][512 n]
    const float* B1 = b1 + (t * NE + e) * NK;
    const int n0 = wc * 128;

    // hoist the x fragments for this wave's 16 rows (4 ks)
    bf16x8 afr[4];
    {
        float xa[4][8];
        #pragma unroll
        for (int ks = 0; ks < 4; ++ks) {
            const float* xp = x + (size_t)((h * MH + l15) * NT + t) * ND + ks * 32 + l4 * 8;
            *(float4*)&xa[ks][0] = *(const float4*)(xp);
            *(float4*)&xa[ks][4] = *(const float4*)(xp + 4);
        }
        #pragma unroll
        for (int ks = 0; ks < 4; ++ks) afr[ks] = cvt8(xa[ks]);
    }

    f32x4 acc[8];
    #pragma unroll
    for (int n = 0; n < 8; ++n) acc[n] = (f32x4){0.f, 0.f, 0.f, 0.f};

    {
        const float* wbase = W1 + (size_t)(l4 * 8) * NK + n0 + l15;
        float wbuf[4][8];
        // prologue: p = 0..3  (ks=0, nt=p)
        #pragma unroll
        for (int q = 0; q < 4; ++q) {
            const float* wp = wbase + q * 16;
            #pragma unroll
            for (int j = 0; j < 8; ++j) wbuf[q][j] = wp[(size_t)j * NK];
        }

        #pragma unroll
        for (int p = 0; p < 32; ++p) {
            const int ks = p >> 3, nt = p & 7;
            // consume slot p&3 first...
            const bf16x8 bfr = cvt8(wbuf[p & 3]);
            // ...then refill the dead slot with iteration p+4's weights
            if (p < 28) {
                const int p4 = p + 4;
                const int ks4 = p4 >> 3, nt4 = p4 & 7;
                const float* wp = wbase + (size_t)(ks4 * 32) * NK + nt4 * 16;
                #pragma unroll
                for (int j = 0; j < 8; ++j) wbuf[p4 & 3][j] = wp[(size_t)j * NK];
            }
            acc[nt] = __builtin_amdgcn_mfma_f32_16x16x32_bf16(afr[ks], bfr, acc[nt], 0, 0, 0);
        }
    }

    // bias + exact-erf gelu -> bf16 H in LDS
    #pragma unroll
    for (int nt = 0; nt < 8; ++nt) {
        const int n = n0 + nt * 16 + l15;
        const float bb = B1[n];
        #pragma unroll
        for (int r = 0; r < 4; ++r) {
            const float hh = acc[nt][r] + bb;
            Hs[h * MH + l4 * 4 + r][n] = f2bf(gelu_erf(hh));
        }
    }
    __syncthreads();

    // ---------------- GEMM2: H[16x512] * W2[512x32-slice]; 32 cols/wave ------
    const float* W2 = w2 + (size_t)((t * NE + e) * NK) * ND;  // [512 k][128 c]
    const float* B2 = b2 + (t * NE + e) * ND;
    const int c0 = wc * 32;

    f32x4 acc2[2];
    #pragma unroll
    for (int n = 0; n < 2; ++n) acc2[n] = (f32x4){0.f, 0.f, 0.f, 0.f};

    {
        const float* w2base = W2 + (size_t)(l4 * 8) * ND + c0 + l15;
        float wb2[4][8];
        // prologue: p = 0..3  (ks=0,1; nt=0,1)
        #pragma unroll
        for (int q = 0; q < 4; ++q) {
            const int ksq = q >> 1, ntq = q & 1;
            const float* wp = w2base + (size_t)(ksq * 32) * ND + ntq * 16;
            #pragma unroll
            for (int j = 0; j < 8; ++j) wb2[q][j] = wp[(size_t)j * ND];
        }

        bf16x8 a2;
        #pragma unroll
        for (int p = 0; p < 32; ++p) {
            const int ks = p >> 1, nt = p & 1;
            if (nt == 0)
                a2 = *(const bf16x8*)&Hs[h * MH + l15][ks * 32 + l4 * 8];
            // consume slot p&3 first...
            const bf16x8 bfr = cvt8(wb2[p & 3]);
            // ...then refill the dead slot with iteration p+4's weights
            if (p < 28) {
                const int p4 = p + 4;
                const int ks4 = p4 >> 1, nt4 = p4 & 1;
                const float* wp = w2base + (size_t)(ks4 * 32) * ND + nt4 * 16;
                #pragma unroll
                for (int j = 0; j < 8; ++j) wb2[p4 & 3][j] = wp[(size_t)j * ND];
            }
            acc2[nt] = __builtin_amdgcn_mfma_f32_16x16x32_bf16(a2, bfr, acc2[nt], 0, 0, 0);
        }
    }

    // gate-weighted epilogue -> ws[e][b][t][d]
    #pragma unroll
    for (int nt = 0; nt < 2; ++nt) {
        const int c = c0 + nt * 16 + l15;
        const float bb = B2[c];
        #pragma unroll
        for (int r = 0; r < 4; ++r) {
            const int b = h * MH + l4 * 4 + r;
            const float v = (acc2[nt][r] + bb) * gate_s[b];
            ws[(size_t)(e * NB * NT + b * NT + t) * ND + c] = v;
        }
    }
}

// ---------------- reduce 4 expert contributions + finalize aux ---------------
__global__ __launch_bounds__(256)
void moe_reduce(const float* __restrict__ ws,
                const float* __restrict__ aux_partial,
                float* __restrict__ out)
{
    const int i = blockIdx.x * blockDim.x + threadIdx.x;
    const int stride = NB * NT * ND / 4;
    const float4* w = (const float4*)ws;
    const float4 a = w[i];
    const float4 b = w[i + stride];
    const float4 c = w[i + 2 * stride];
    const float4 d = w[i + 3 * stride];
    float4 r;
    r.x = a.x + b.x + c.x + d.x;
    r.y = a.y + b.y + c.y + d.y;
    r.z = a.z + b.z + c.z + d.z;
    r.w = a.w + b.w + c.w + d.w;
    ((float4*)out)[i] = r;

    if (blockIdx.x == 0) {
        const int tid = threadIdx.x;
        float s = aux_partial[tid] + aux_partial[tid + 256];
        #pragma unroll
        for (int off = 32; off > 0; off >>= 1) s += __shfl_xor(s, off);
        __shared__ float wsum[4];
        if ((tid & 63) == 0) wsum[tid >> 6] = s;
        __syncthreads();
        if (tid == 0)
            out[NB * NT * ND] = (wsum[0] + wsum[1] + wsum[2] + wsum[3]) *
                                (0.01f / (NB * NT));
    }
}

// ---------------- fallback (ws too small): self-contained, atomics -----------
__global__ __launch_bounds__(256, 2)
void moe_main_fb(const float* __restrict__ x,
                 const float* __restrict__ w1,
                 const float* __restrict__ b1,
                 const float* __restrict__ w2,
                 const float* __restrict__ b2,
                 const float* __restrict__ rw,
                 const float* __restrict__ rb,
                 float* __restrict__ out)
{
    const int blk  = blockIdx.x;
    const int t    = blk >> 2;
    const int e    = blk & 3;
    const int tid  = threadIdx.x;
    const int lane = tid & 63;
    const int wave = tid >> 6;
    const int l15  = lane & 15;
    const int l4   = lane >> 4;

    __shared__ short Hs[NB][NK + 8];
    __shared__ float gate_s[NB];

    if (tid < NB) {
        const int b = tid;
        const float* xr = x + (b * NT + t) * ND;
        float l0 = rb[0], l1 = rb[1], l2 = rb[2], l3 = rb[3];
        #pragma unroll 8
        for (int d = 0; d < ND; ++d) {
            const float xv = xr[d];
            const float* w = rw + d * NE;
            l0 += xv * w[0]; l1 += xv * w[1]; l2 += xv * w[2]; l3 += xv * w[3];
        }
        l0 = fmaxf(l0, 0.f); l1 = fmaxf(l1, 0.f); l2 = fmaxf(l2, 0.f); l3 = fmaxf(l3, 0.f);
        const float ss  = l0 + l1 + l2 + l3;
        const float inv = 1.f / (ss + 1e-9f);
        const float ge  = (e == 0) ? l0 : (e == 1) ? l1 : (e == 2) ? l2 : l3;
        gate_s[b] = ge * inv;
        if (e == 0) {
            float aux = ss * inv;
            #pragma unroll
            for (int off = 32; off > 0; off >>= 1) aux += __shfl_down(aux, off);
            if (lane == 0) atomicAdd(out + NB * NT * ND, aux * (0.01f / (NB * NT)));
        }
    }
    __syncthreads();

    const float* W1 = w1 + (size_t)((t * NE + e) * ND) * NK;
    const float* B1 = b1 + (t * NE + e) * NK;
    const int n0 = wave * 128;

    f32x4 acc[4][8];
    #pragma unroll
    for (int m = 0; m < 4; ++m)
        #pragma unroll
        for (int n = 0; n < 8; ++n) acc[m][n] = (f32x4){0.f, 0.f, 0.f, 0.f};

    #pragma unroll
    for (int ks = 0; ks < 4; ++ks) {
        const int d0 = ks * 32 + l4 * 8;
        bf16x8 afr[4];
        #pragma unroll
        for (int m = 0; m < 4; ++m) {
            const int b = m * 16 + l15;
            const float* xp = x + (b * NT + t) * ND + d0;
            float xf[8];
            *(float4*)&xf[0] = *(const float4*)(xp);
            *(float4*)&xf[4] = *(const float4*)(xp + 4);
            afr[m] = cvt8(xf);
        }
        #pragma unroll
        for (int nt = 0; nt < 8; ++nt) {
            const int n = n0 + nt * 16 + l15;
            const float* wp = W1 + (size_t)d0 * NK + n;
            float wf[8];
            #pragma unroll
            for (int j = 0; j < 8; ++j) wf[j] = wp[(size_t)j * NK];
            const bf16x8 bfr = cvt8(wf);
            #pragma unroll
            for (int m = 0; m < 4; ++m)
                acc[m][nt] = __builtin_amdgcn_mfma_f32_16x16x32_bf16(afr[m], bfr, acc[m][nt], 0, 0, 0);
        }
    }

    #pragma unroll
    for (int nt = 0; nt < 8; ++nt) {
        const int n = n0 + nt * 16 + l15;
        const float bb = B1[n];
        #pragma unroll
        for (int m = 0; m < 4; ++m) {
            const int row = m * 16 + l4 * 4;
            #pragma unroll
            for (int r = 0; r < 4; ++r) {
                const float hh = acc[m][nt][r] + bb;
                Hs[row + r][n] = f2bf(gelu_erf(hh));
            }
        }
    }
    __syncthreads();

    const float* W2 = w2 + (size_t)((t * NE + e) * NK) * ND;
    const float* B2 = b2 + (t * NE + e) * ND;
    const int c0 = wave * 32;

    f32x4 acc2[4][2];
    #pragma unroll
    for (int m = 0; m < 4; ++m)
        #pragma unroll
        for (int n = 0; n < 2; ++n) acc2[m][n] = (f32x4){0.f, 0.f, 0.f, 0.f};

    #pragma unroll 4
    for (int ks = 0; ks < 16; ++ks) {
        const int k0 = ks * 32 + l4 * 8;
        bf16x8 afr[4];
        #pragma unroll
        for (int m = 0; m < 4; ++m)
            afr[m] = *(const bf16x8*)(&Hs[m * 16 + l15][k0]);
        #pragma unroll
        for (int nt = 0; nt < 2; ++nt) {
            const int c = c0 + nt * 16 + l15;
            const float* wp = W2 + (size_t)k0 * ND + c;
            float wf[8];
            #pragma unroll
            for (int j = 0; j < 8; ++j) wf[j] = wp[(size_t)j * ND];
            const bf16x8 bfr = cvt8(wf);
            #pragma unroll
            for (int m = 0; m < 4; ++m)
                acc2[m][nt] = __builtin_amdgcn_mfma_f32_16x16x32_bf16(afr[m], bfr, acc2[m][nt], 0, 0, 0);
        }
    }

    #pragma unroll
    for (int nt = 0; nt < 2; ++nt) {
        const int c = c0 + nt * 16 + l15;
        const float bb = B2[c];
        #pragma unroll
        for (int m = 0; m < 4; ++m) {
            #pragma unroll
            for (int r = 0; r < 4; ++r) {
                const int b = m * 16 + l4 * 4 + r;
                const float v = (acc2[m][nt][r] + bb) * gate_s[b];
                atomicAdd(out + (size_t)(b * NT + t) * ND + c, v);
            }
        }
    }
}

extern "C" void kernel_launch(void* const* d_in, const int* in_sizes, int n_in,
                              void* d_out, int out_size, void* d_ws, size_t ws_size,
                              hipStream_t stream) {
    const float* x  = (const float*)d_in[0];
    const float* w1 = (const float*)d_in[1];
    const float* b1 = (const float*)d_in[2];
    const float* w2 = (const float*)d_in[3];
    const float* b2 = (const float*)d_in[4];
    const float* rw = (const float*)d_in[5];
    const float* rb = (const float*)d_in[6];
    float* out = (float*)d_out;

    const size_t contrib_elems = (size_t)NE * NB * NT * ND;           // 16 MiB
    const size_t gates_elems   = (size_t)NB * NT * NE;
    const size_t aux_elems     = 512;
    const size_t ws_need = (contrib_elems + gates_elems + aux_elems) * sizeof(float);

    if (ws_size >= ws_need) {
        float* contrib = (float*)d_ws;
        float* gates   = contrib + contrib_elems;
        float* auxp    = gates + gates_elems;

        moe_gates<<<512, 256, 0, stream>>>(x, rw, rb, gates, auxp);
        moe_main<<<NT * NE, 1024, 0, stream>>>(x, w1, b1, w2, b2, gates, contrib);
        moe_reduce<<<(NB * NT * ND / 4) / 256, 256, 0, stream>>>(contrib, auxp, out);
    } else {
        hipMemsetAsync(d_out, 0, (size_t)(NB * NT * ND + 1) * sizeof(float), stream);
        moe_main_fb<<<NT * NE, 256, 0, stream>>>(x, w1, b1, w2, b2, rw, rb, out);
    }
}

// Round 16
// 70.877 us; speedup vs baseline: 2.5732x; 2.1049x over previous
//
#include <hip/hip_runtime.h>
#include <hip/hip_bf16.h>

#define NB 64    // batch
#define NT 128   // tokens (seq)
#define NE 4     // experts
#define ND 128   // model dim
#define NK 512   // ffn hidden dim

typedef __attribute__((ext_vector_type(8))) short bf16x8;
typedef __attribute__((ext_vector_type(4))) float f32x4;

__device__ __forceinline__ short f2bf(float f) {
    union { __hip_bfloat16 b; short s; } u;
    u.b = __float2bfloat16(f);
    return u.s;
}

__device__ __forceinline__ bf16x8 cvt8(const float* f) {
    bf16x8 r;
    #pragma unroll
    for (int j = 0; j < 8; ++j) r[j] = f2bf(f[j]);
    return r;
}

__device__ __forceinline__ float gelu_erf(float x) {
    return 0.5f * x * (1.0f + erff(x * 0.70710678118654752f));
}

// ---------------- router: one wave per token (4 tokens per wave via loop) ----
__global__ __launch_bounds__(256)
void moe_gates(const float* __restrict__ x,
               const float* __restrict__ rw,
               const float* __restrict__ rb,
               float* __restrict__ gates_ws,
               float* __restrict__ aux_partial)
{
    const int tid  = threadIdx.x;
    const int lane = tid & 63;
    const int wave = tid >> 6;
    __shared__ float waux[4];

    const float4 rw0 = *(const float4*)(rw + lane * 4);
    const float4 rw1 = *(const float4*)(rw + (64 + lane) * 4);
    const float4 rbv = *(const float4*)rb;

    float aux = 0.f;
    #pragma unroll
    for (int i = 0; i < 4; ++i) {
        const int tok = (blockIdx.x * 4 + wave) * 4 + i;       // b*NT + t
        const float x0 = x[tok * ND + lane];
        const float x1 = x[tok * ND + 64 + lane];
        float p0 = x0 * rw0.x + x1 * rw1.x;
        float p1 = x0 * rw0.y + x1 * rw1.y;
        float p2 = x0 * rw0.z + x1 * rw1.z;
        float p3 = x0 * rw0.w + x1 * rw1.w;
        #pragma unroll
        for (int off = 32; off > 0; off >>= 1) {
            p0 += __shfl_xor(p0, off);
            p1 += __shfl_xor(p1, off);
            p2 += __shfl_xor(p2, off);
            p3 += __shfl_xor(p3, off);
        }
        if (lane == 0) {
            p0 = fmaxf(p0 + rbv.x, 0.f);
            p1 = fmaxf(p1 + rbv.y, 0.f);
            p2 = fmaxf(p2 + rbv.z, 0.f);
            p3 = fmaxf(p3 + rbv.w, 0.f);
            const float s   = p0 + p1 + p2 + p3;
            const float inv = 1.f / (s + 1e-9f);
            float4 g; g.x = p0 * inv; g.y = p1 * inv; g.z = p2 * inv; g.w = p3 * inv;
            *(float4*)(gates_ws + tok * NE) = g;
            aux += s * inv;
        }
    }
    if (lane == 0) waux[wave] = aux;
    __syncthreads();
    if (tid == 0)
        aux_partial[blockIdx.x] = waux[0] + waux[1] + waux[2] + waux[3];
}

// ---------------- main: ONE block per (t, e); 512 threads = 8 waves ----------
// Each wave owns a DISJOINT weight slice: GEMM1 cols [w*64, w*64+64),
// GEMM2 cols [w*16, w*16+16). No weight byte is read twice anywhere on the
// chip (unique demand ~266 MB = the 42 us roofline numerator). Depth-4
// consume-first register ring per wave (R11-proven MLP). Exactly ONE
// __syncthreads in the kernel (H handoff) -> no per-K-step vmcnt(0) drains.
__global__ __launch_bounds__(512, 4)
void moe_main(const float* __restrict__ x,
              const float* __restrict__ w1,
              const float* __restrict__ b1,
              const float* __restrict__ w2,
              const float* __restrict__ b2,
              const float* __restrict__ gates_ws,
              float* __restrict__ ws)
{
    const int bid  = blockIdx.x;        // (t,e)
    const int t    = bid >> 2;
    const int e    = bid & 3;
    const int tid  = threadIdx.x;
    const int lane = tid & 63;
    const int wave = tid >> 6;          // 0..7
    const int l15  = lane & 15;
    const int l4   = lane >> 4;

    __shared__ short Hs[NB][NK + 8];    // 64 x 520 bf16 bits = 66,560 B
    __shared__ float gate_s[NB];

    if (tid < NB)
        gate_s[tid] = gates_ws[(tid * NT + t) * NE + e];

    // ---------------- GEMM1: X[64x128] * W1[128x(64-slice)] ------------------
    const float* W1 = w1 + (size_t)((t * NE + e) * ND) * NK;  // [128 d][512 n]
    const float* B1 = b1 + (t * NE + e) * NK;
    const int n0 = wave * 64;           // disjoint 64-col slice per wave

    f32x4 acc[4][4];                    // m-frags x nt-frags (64 rows x 64 cols)
    #pragma unroll
    for (int m = 0; m < 4; ++m)
        #pragma unroll
        for (int n = 0; n < 4; ++n) acc[m][n] = (f32x4){0.f, 0.f, 0.f, 0.f};

    {
        const float* wbase = W1 + (size_t)(l4 * 8) * NK + n0 + l15;
        float wbuf[4][8];
        // prologue: p = 0..3  (ks=0, nt=p)
        #pragma unroll
        for (int q = 0; q < 4; ++q) {
            const float* wp = wbase + q * 16;
            #pragma unroll
            for (int j = 0; j < 8; ++j) wbuf[q][j] = wp[(size_t)j * NK];
        }

        bf16x8 afr[4];
        #pragma unroll
        for (int p = 0; p < 16; ++p) {
            const int ks = p >> 2, nt = p & 3;
            if (nt == 0) {
                const int d0 = ks * 32 + l4 * 8;
                #pragma unroll
                for (int m = 0; m < 4; ++m) {
                    const float* xp = x + (size_t)((m * 16 + l15) * NT + t) * ND + d0;
                    float xf[8];
                    *(float4*)&xf[0] = *(const float4*)(xp);
                    *(float4*)&xf[4] = *(const float4*)(xp + 4);
                    afr[m] = cvt8(xf);
                }
            }
            // consume slot p&3 first...
            const bf16x8 bfr = cvt8(wbuf[p & 3]);
            // ...then refill the dead slot with iteration p+4's weights
            if (p < 12) {
                const int p4 = p + 4;
                const int ks4 = p4 >> 2, nt4 = p4 & 3;
                const float* wp = wbase + (size_t)(ks4 * 32) * NK + nt4 * 16;
                #pragma unroll
                for (int j = 0; j < 8; ++j) wbuf[p4 & 3][j] = wp[(size_t)j * NK];
            }
            #pragma unroll
            for (int m = 0; m < 4; ++m)
                acc[m][nt] = __builtin_amdgcn_mfma_f32_16x16x32_bf16(afr[m], bfr, acc[m][nt], 0, 0, 0);
        }
    }

    // bias + exact-erf gelu -> bf16 H in LDS
    #pragma unroll
    for (int nt = 0; nt < 4; ++nt) {
        const int n = n0 + nt * 16 + l15;
        const float bb = B1[n];
        #pragma unroll
        for (int m = 0; m < 4; ++m) {
            const int row = m * 16 + l4 * 4;
            #pragma unroll
            for (int r = 0; r < 4; ++r) {
                const float hh = acc[m][nt][r] + bb;
                Hs[row + r][n] = f2bf(gelu_erf(hh));
            }
        }
    }
    __syncthreads();   // the ONLY barrier

    // ---------------- GEMM2: H[64x512] * W2[512x(16-slice)] ------------------
    const float* W2 = w2 + (size_t)((t * NE + e) * NK) * ND;  // [512 k][128 c]
    const float* B2 = b2 + (t * NE + e) * ND;
    const int c0 = wave * 16;           // disjoint 16-col slice per wave

    f32x4 acc2[4];                      // 4 m-frags (64 rows x 16 cols)
    #pragma unroll
    for (int m = 0; m < 4; ++m) acc2[m] = (f32x4){0.f, 0.f, 0.f, 0.f};

    {
        const float* w2base = W2 + (size_t)(l4 * 8) * ND + c0 + l15;
        float wb2[4][8];
        // prologue: p = 0..3 (ks=p)
        #pragma unroll
        for (int q = 0; q < 4; ++q) {
            const float* wp = w2base + (size_t)(q * 32) * ND;
            #pragma unroll
            for (int j = 0; j < 8; ++j) wb2[q][j] = wp[(size_t)j * ND];
        }

        bf16x8 a2[4];
        #pragma unroll
        for (int p = 0; p < 16; ++p) {
            const int ks = p;
            const int k0 = ks * 32 + l4 * 8;
            #pragma unroll
            for (int m = 0; m < 4; ++m)
                a2[m] = *(const bf16x8*)(&Hs[m * 16 + l15][k0]);
            // consume slot p&3 first...
            const bf16x8 bfr = cvt8(wb2[p & 3]);
            // ...then refill the dead slot with iteration p+4's weights
            if (p < 12) {
                const int ks4 = p + 4;
                const float* wp = w2base + (size_t)(ks4 * 32) * ND;
                #pragma unroll
                for (int j = 0; j < 8; ++j) wb2[(p + 4) & 3][j] = wp[(size_t)j * ND];
            }
            #pragma unroll
            for (int m = 0; m < 4; ++m)
                acc2[m] = __builtin_amdgcn_mfma_f32_16x16x32_bf16(a2[m], bfr, acc2[m], 0, 0, 0);
        }
    }

    // gate-weighted epilogue -> ws[e][b][t][d]
    {
        const int c = c0 + l15;
        const float bb = B2[c];
        #pragma unroll
        for (int m = 0; m < 4; ++m) {
            #pragma unroll
            for (int r = 0; r < 4; ++r) {
                const int b = m * 16 + l4 * 4 + r;
                const float v = (acc2[m][r] + bb) * gate_s[b];
                ws[(size_t)(e * NB * NT + b * NT + t) * ND + c] = v;
            }
        }
    }
}

// ---------------- reduce 4 expert contributions + finalize aux ---------------
__global__ __launch_bounds__(256)
void moe_reduce(const float* __restrict__ ws,
                const float* __restrict__ aux_partial,
                float* __restrict__ out)
{
    const int i = blockIdx.x * blockDim.x + threadIdx.x;
    const int stride = NB * NT * ND / 4;
    const float4* w = (const float4*)ws;
    const float4 a = w[i];
    const float4 b = w[i + stride];
    const float4 c = w[i + 2 * stride];
    const float4 d = w[i + 3 * stride];
    float4 r;
    r.x = a.x + b.x + c.x + d.x;
    r.y = a.y + b.y + c.y + d.y;
    r.z = a.z + b.z + c.z + d.z;
    r.w = a.w + b.w + c.w + d.w;
    ((float4*)out)[i] = r;

    if (blockIdx.x == 0) {
        const int tid = threadIdx.x;
        float s = aux_partial[tid] + aux_partial[tid + 256];
        #pragma unroll
        for (int off = 32; off > 0; off >>= 1) s += __shfl_xor(s, off);
        __shared__ float wsum[4];
        if ((tid & 63) == 0) wsum[tid >> 6] = s;
        __syncthreads();
        if (tid == 0)
            out[NB * NT * ND] = (wsum[0] + wsum[1] + wsum[2] + wsum[3]) *
                                (0.01f / (NB * NT));
    }
}

// ---------------- fallback (ws too small): self-contained, atomics -----------
__global__ __launch_bounds__(256, 2)
void moe_main_fb(const float* __restrict__ x,
                 const float* __restrict__ w1,
                 const float* __restrict__ b1,
                 const float* __restrict__ w2,
                 const float* __restrict__ b2,
                 const float* __restrict__ rw,
                 const float* __restrict__ rb,
                 float* __restrict__ out)
{
    const int blk  = blockIdx.x;
    const int t    = blk >> 2;
    const int e    = blk & 3;
    const int tid  = threadIdx.x;
    const int lane = tid & 63;
    const int wave = tid >> 6;
    const int l15  = lane & 15;
    const int l4   = lane >> 4;

    __shared__ short Hs[NB][NK + 8];
    __shared__ float gate_s[NB];

    if (tid < NB) {
        const int b = tid;
        const float* xr = x + (b * NT + t) * ND;
        float l0 = rb[0], l1 = rb[1], l2 = rb[2], l3 = rb[3];
        #pragma unroll 8
        for (int d = 0; d < ND; ++d) {
            const float xv = xr[d];
            const float* w = rw + d * NE;
            l0 += xv * w[0]; l1 += xv * w[1]; l2 += xv * w[2]; l3 += xv * w[3];
        }
        l0 = fmaxf(l0, 0.f); l1 = fmaxf(l1, 0.f); l2 = fmaxf(l2, 0.f); l3 = fmaxf(l3, 0.f);
        const float ss  = l0 + l1 + l2 + l3;
        const float inv = 1.f / (ss + 1e-9f);
        const float ge  = (e == 0) ? l0 : (e == 1) ? l1 : (e == 2) ? l2 : l3;
        gate_s[b] = ge * inv;
        if (e == 0) {
            float aux = ss * inv;
            #pragma unroll
            for (int off = 32; off > 0; off >>= 1) aux += __shfl_down(aux, off);
            if (lane == 0) atomicAdd(out + NB * NT * ND, aux * (0.01f / (NB * NT)));
        }
    }
    __syncthreads();

    const float* W1 = w1 + (size_t)((t * NE + e) * ND) * NK;
    const float* B1 = b1 + (t * NE + e) * NK;
    const int n0 = wave * 128;

    f32x4 acc[4][8];
    #pragma unroll
    for (int m = 0; m < 4; ++m)
        #pragma unroll
        for (int n = 0; n < 8; ++n) acc[m][n] = (f32x4){0.f, 0.f, 0.f, 0.f};

    #pragma unroll
    for (int ks = 0; ks < 4; ++ks) {
        const int d0 = ks * 32 + l4 * 8;
        bf16x8 afr[4];
        #pragma unroll
        for (int m = 0; m < 4; ++m) {
            const int b = m * 16 + l15;
            const float* xp = x + (b * NT + t) * ND + d0;
            float xf[8];
            *(float4*)&xf[0] = *(const float4*)(xp);
            *(float4*)&xf[4] = *(const float4*)(xp + 4);
            afr[m] = cvt8(xf);
        }
        #pragma unroll
        for (int nt = 0; nt < 8; ++nt) {
            const int n = n0 + nt * 16 + l15;
            const float* wp = W1 + (size_t)d0 * NK + n;
            float wf[8];
            #pragma unroll
            for (int j = 0; j < 8; ++j) wf[j] = wp[(size_t)j * NK];
            const bf16x8 bfr = cvt8(wf);
            #pragma unroll
            for (int m = 0; m < 4; ++m)
                acc[m][nt] = __builtin_amdgcn_mfma_f32_16x16x32_bf16(afr[m], bfr, acc[m][nt], 0, 0, 0);
        }
    }

    #pragma unroll
    for (int nt = 0; nt < 8; ++nt) {
        const int n = n0 + nt * 16 + l15;
        const float bb = B1[n];
        #pragma unroll
        for (int m = 0; m < 4; ++m) {
            const int row = m * 16 + l4 * 4;
            #pragma unroll
            for (int r = 0; r < 4; ++r) {
                const float hh = acc[m][nt][r] + bb;
                Hs[row + r][n] = f2bf(gelu_erf(hh));
            }
        }
    }
    __syncthreads();

    const float* W2 = w2 + (size_t)((t * NE + e) * NK) * ND;
    const float* B2 = b2 + (t * NE + e) * ND;
    const int c0 = wave * 32;

    f32x4 acc2[4][2];
    #pragma unroll
    for (int m = 0; m < 4; ++m)
        #pragma unroll
        for (int n = 0; n < 2; ++n) acc2[m][n] = (f32x4){0.f, 0.f, 0.f, 0.f};

    #pragma unroll 4
    for (int ks = 0; ks < 16; ++ks) {
        const int k0 = ks * 32 + l4 * 8;
        bf16x8 afr[4];
        #pragma unroll
        for (int m = 0; m < 4; ++m)
            afr[m] = *(const bf16x8*)(&Hs[m * 16 + l15][k0]);
        #pragma unroll
        for (int nt = 0; nt < 2; ++nt) {
            const int c = c0 + nt * 16 + l15;
            const float* wp = W2 + (size_t)k0 * ND + c;
            float wf[8];
            #pragma unroll
            for (int j = 0; j < 8; ++j) wf[j] = wp[(size_t)j * ND];
            const bf16x8 bfr = cvt8(wf);
            #pragma unroll
            for (int m = 0; m < 4; ++m)
                acc2[m][nt] = __builtin_amdgcn_mfma_f32_16x16x32_bf16(afr[m], bfr, acc2[m][nt], 0, 0, 0);
        }
    }

    #pragma unroll
    for (int nt = 0; nt < 2; ++nt) {
        const int c = c0 + nt * 16 + l15;
        const float bb = B2[c];
        #pragma unroll
        for (int m = 0; m < 4; ++m) {
            #pragma unroll
            for (int r = 0; r < 4; ++r) {
                const int b = m * 16 + l4 * 4 + r;
                const float v = (acc2[m][nt][r] + bb) * gate_s[b];
                atomicAdd(out + (size_t)(b * NT + t) * ND + c, v);
            }
        }
    }
}

extern "C" void kernel_launch(void* const* d_in, const int* in_sizes, int n_in,
                              void* d_out, int out_size, void* d_ws, size_t ws_size,
                              hipStream_t stream) {
    const float* x  = (const float*)d_in[0];
    const float* w1 = (const float*)d_in[1];
    const float* b1 = (const float*)d_in[2];
    const float* w2 = (const float*)d_in[3];
    const float* b2 = (const float*)d_in[4];
    const float* rw = (const float*)d_in[5];
    const float* rb = (const float*)d_in[6];
    float* out = (float*)d_out;

    const size_t contrib_elems = (size_t)NE * NB * NT * ND;           // 16 MiB
    const size_t gates_elems   = (size_t)NB * NT * NE;
    const size_t aux_elems     = 512;
    const size_t ws_need = (contrib_elems + gates_elems + aux_elems) * sizeof(float);

    if (ws_size >= ws_need) {
        float* contrib = (float*)d_ws;
        float* gates   = contrib + contrib_elems;
        float* auxp    = gates + gates_elems;

        moe_gates<<<512, 256, 0, stream>>>(x, rw, rb, gates, auxp);
        moe_main<<<NT * NE, 512, 0, stream>>>(x, w1, b1, w2, b2, gates, contrib);
        moe_reduce<<<(NB * NT * ND / 4) / 256, 256, 0, stream>>>(contrib, auxp, out);
    } else {
        hipMemsetAsync(d_out, 0, (size_t)(NB * NT * ND + 1) * sizeof(float), stream);
        moe_main_fb<<<NT * NE, 256, 0, stream>>>(x, w1, b1, w2, b2, rw, rb, out);
    }
}

// Round 17
// 61.871 us; speedup vs baseline: 2.9478x; 1.1456x over previous
//
#include <hip/hip_runtime.h>
#include <hip/hip_bf16.h>

#define NB 64    // batch
#define NT 128   // tokens (seq)
#define NE 4     // experts
#define ND 128   // model dim
#define NK 512   // ffn hidden dim

typedef __attribute__((ext_vector_type(8))) short bf16x8;
typedef __attribute__((ext_vector_type(4))) short bf16x4;
typedef __attribute__((ext_vector_type(4))) float f32x4;

__device__ __forceinline__ short f2bf(float f) {
    union { __hip_bfloat16 b; short s; } u;
    u.b = __float2bfloat16(f);
    return u.s;
}

__device__ __forceinline__ bf16x8 cvt8(const float* f) {
    bf16x8 r;
    #pragma unroll
    for (int j = 0; j < 8; ++j) r[j] = f2bf(f[j]);
    return r;
}

__device__ __forceinline__ bf16x4 cvt4(float4 f) {
    bf16x4 r;
    r[0] = f2bf(f.x); r[1] = f2bf(f.y); r[2] = f2bf(f.z); r[3] = f2bf(f.w);
    return r;
}

__device__ __forceinline__ float gelu_erf(float x) {
    return 0.5f * x * (1.0f + erff(x * 0.70710678118654752f));
}

// ---------------- router: one wave per token (4 tokens per wave via loop) ----
__global__ __launch_bounds__(256)
void moe_gates(const float* __restrict__ x,
               const float* __restrict__ rw,
               const float* __restrict__ rb,
               float* __restrict__ gates_ws,
               float* __restrict__ aux_partial)
{
    const int tid  = threadIdx.x;
    const int lane = tid & 63;
    const int wave = tid >> 6;
    __shared__ float waux[4];

    const float4 rw0 = *(const float4*)(rw + lane * 4);
    const float4 rw1 = *(const float4*)(rw + (64 + lane) * 4);
    const float4 rbv = *(const float4*)rb;

    float aux = 0.f;
    #pragma unroll
    for (int i = 0; i < 4; ++i) {
        const int tok = (blockIdx.x * 4 + wave) * 4 + i;       // b*NT + t
        const float x0 = x[tok * ND + lane];
        const float x1 = x[tok * ND + 64 + lane];
        float p0 = x0 * rw0.x + x1 * rw1.x;
        float p1 = x0 * rw0.y + x1 * rw1.y;
        float p2 = x0 * rw0.z + x1 * rw1.z;
        float p3 = x0 * rw0.w + x1 * rw1.w;
        #pragma unroll
        for (int off = 32; off > 0; off >>= 1) {
            p0 += __shfl_xor(p0, off);
            p1 += __shfl_xor(p1, off);
            p2 += __shfl_xor(p2, off);
            p3 += __shfl_xor(p3, off);
        }
        if (lane == 0) {
            p0 = fmaxf(p0 + rbv.x, 0.f);
            p1 = fmaxf(p1 + rbv.y, 0.f);
            p2 = fmaxf(p2 + rbv.z, 0.f);
            p3 = fmaxf(p3 + rbv.w, 0.f);
            const float s   = p0 + p1 + p2 + p3;
            const float inv = 1.f / (s + 1e-9f);
            float4 g; g.x = p0 * inv; g.y = p1 * inv; g.z = p2 * inv; g.w = p3 * inv;
            *(float4*)(gates_ws + tok * NE) = g;
            aux += s * inv;
        }
    }
    if (lane == 0) waux[wave] = aux;
    __syncthreads();
    if (tid == 0)
        aux_partial[blockIdx.x] = waux[0] + waux[1] + waux[2] + waux[3];
}

// ---------------- main: ONE block per (t, e); 512 threads = 8 waves ----------
// Disjoint weight slices per wave (unique HBM fetch, R16-proven 146 MB).
// NEW vs R16: x-tile staged ONCE into LDS as bf16 (Xs, aliased into the Hs
// region) -> kills the 8x x re-read (256->32 KB/block) that was saturating
// the ~25 GB/s/CU demand-delivery ceiling. Depth-4 consume-first W-ring.
__global__ __launch_bounds__(512, 4)
void moe_main(const float* __restrict__ x,
              const float* __restrict__ w1,
              const float* __restrict__ b1,
              const float* __restrict__ w2,
              const float* __restrict__ b2,
              const float* __restrict__ gates_ws,
              float* __restrict__ ws)
{
    const int bid  = blockIdx.x;        // (t,e)
    const int t    = bid >> 2;
    const int e    = bid & 3;
    const int tid  = threadIdx.x;
    const int lane = tid & 63;
    const int wave = tid >> 6;          // 0..7
    const int l15  = lane & 15;
    const int l4   = lane >> 4;

    // LDS: Hs [64][520] bf16 = 66,560 B at offset 0
    //      Xs [64][136] bf16 = 17,408 B at offset 0 (ALIASES Hs; dead before
    //                                               Hs writes, barrier-fenced)
    //      gate_s [64] f32 at 66,560  -> total 66,816 B; 2 blocks/CU
    __shared__ __align__(16) char smem[66816];
    short* Hs     = (short*)smem;                 // [64][520]
    short* Xs     = (short*)smem;                 // [64][136]
    float* gate_s = (float*)(smem + 66560);

    if (tid < NB)
        gate_s[tid] = gates_ws[(tid * NT + t) * NE + e];

    // ---------------- stage x-tile -> LDS bf16 (once per block) --------------
    {
        float4 xv[4];
        #pragma unroll
        for (int q = 0; q < 4; ++q) {
            const int f   = q * 512 + tid;        // float4 index, 2048 total
            const int row = f >> 5;               // 32 float4 per row
            const int c4  = f & 31;
            xv[q] = *(const float4*)(x + (size_t)(row * NT + t) * ND + c4 * 4);
        }
        #pragma unroll
        for (int q = 0; q < 4; ++q) {
            const int f   = q * 512 + tid;
            const int row = f >> 5;
            const int c4  = f & 31;
            *(bf16x4*)&Xs[row * 136 + c4 * 4] = cvt4(xv[q]);
        }
    }
    __syncthreads();

    // ---------------- GEMM1: X[64x128] * W1[128x(64-slice)] ------------------
    const float* W1 = w1 + (size_t)((t * NE + e) * ND) * NK;  // [128 d][512 n]
    const float* B1 = b1 + (t * NE + e) * NK;
    const int n0 = wave * 64;           // disjoint 64-col slice per wave

    f32x4 acc[4][4];                    // 64 rows x 64 cols per wave
    #pragma unroll
    for (int m = 0; m < 4; ++m)
        #pragma unroll
        for (int n = 0; n < 4; ++n) acc[m][n] = (f32x4){0.f, 0.f, 0.f, 0.f};

    {
        const float* wbase = W1 + (size_t)(l4 * 8) * NK + n0 + l15;
        float wbuf[4][8];
        // prologue: p = 0..3  (ks=0, nt=p)
        #pragma unroll
        for (int q = 0; q < 4; ++q) {
            const float* wp = wbase + q * 16;
            #pragma unroll
            for (int j = 0; j < 8; ++j) wbuf[q][j] = wp[(size_t)j * NK];
        }

        bf16x8 afr[4];
        #pragma unroll
        for (int p = 0; p < 16; ++p) {
            const int ks = p >> 2, nt = p & 3;
            if (nt == 0) {
                const int d0 = ks * 32 + l4 * 8;
                #pragma unroll
                for (int m = 0; m < 4; ++m)
                    afr[m] = *(const bf16x8*)&Xs[(m * 16 + l15) * 136 + d0];
            }
            // consume slot p&3 first...
            const bf16x8 bfr = cvt8(wbuf[p & 3]);
            // ...then refill the dead slot with iteration p+4's weights
            if (p < 12) {
                const int p4 = p + 4;
                const int ks4 = p4 >> 2, nt4 = p4 & 3;
                const float* wp = wbase + (size_t)(ks4 * 32) * NK + nt4 * 16;
                #pragma unroll
                for (int j = 0; j < 8; ++j) wbuf[p4 & 3][j] = wp[(size_t)j * NK];
            }
            #pragma unroll
            for (int m = 0; m < 4; ++m)
                acc[m][nt] = __builtin_amdgcn_mfma_f32_16x16x32_bf16(afr[m], bfr, acc[m][nt], 0, 0, 0);
        }
    }
    __syncthreads();   // all Xs reads done before Hs overwrites the region

    // bias + exact-erf gelu -> bf16 H in LDS
    #pragma unroll
    for (int nt = 0; nt < 4; ++nt) {
        const int n = n0 + nt * 16 + l15;
        const float bb = B1[n];
        #pragma unroll
        for (int m = 0; m < 4; ++m) {
            const int row = m * 16 + l4 * 4;
            #pragma unroll
            for (int r = 0; r < 4; ++r) {
                const float hh = acc[m][nt][r] + bb;
                Hs[(row + r) * 520 + n] = f2bf(gelu_erf(hh));
            }
        }
    }
    __syncthreads();

    // ---------------- GEMM2: H[64x512] * W2[512x(16-slice)] ------------------
    const float* W2 = w2 + (size_t)((t * NE + e) * NK) * ND;  // [512 k][128 c]
    const float* B2 = b2 + (t * NE + e) * ND;
    const int c0 = wave * 16;           // disjoint 16-col slice per wave

    f32x4 acc2[4];                      // 64 rows x 16 cols per wave
    #pragma unroll
    for (int m = 0; m < 4; ++m) acc2[m] = (f32x4){0.f, 0.f, 0.f, 0.f};

    {
        const float* w2base = W2 + (size_t)(l4 * 8) * ND + c0 + l15;
        float wb2[4][8];
        // prologue: p = 0..3 (ks=p)
        #pragma unroll
        for (int q = 0; q < 4; ++q) {
            const float* wp = w2base + (size_t)(q * 32) * ND;
            #pragma unroll
            for (int j = 0; j < 8; ++j) wb2[q][j] = wp[(size_t)j * ND];
        }

        bf16x8 a2[4];
        #pragma unroll
        for (int p = 0; p < 16; ++p) {
            const int k0 = p * 32 + l4 * 8;
            #pragma unroll
            for (int m = 0; m < 4; ++m)
                a2[m] = *(const bf16x8*)(&Hs[(m * 16 + l15) * 520 + k0]);
            // consume slot p&3 first...
            const bf16x8 bfr = cvt8(wb2[p & 3]);
            // ...then refill the dead slot with iteration p+4's weights
            if (p < 12) {
                const int ks4 = p + 4;
                const float* wp = w2base + (size_t)(ks4 * 32) * ND;
                #pragma unroll
                for (int j = 0; j < 8; ++j) wb2[(p + 4) & 3][j] = wp[(size_t)j * ND];
            }
            #pragma unroll
            for (int m = 0; m < 4; ++m)
                acc2[m] = __builtin_amdgcn_mfma_f32_16x16x32_bf16(a2[m], bfr, acc2[m], 0, 0, 0);
        }
    }

    // gate-weighted epilogue -> ws[e][b][t][d]
    {
        const int c = c0 + l15;
        const float bb = B2[c];
        #pragma unroll
        for (int m = 0; m < 4; ++m) {
            #pragma unroll
            for (int r = 0; r < 4; ++r) {
                const int b = m * 16 + l4 * 4 + r;
                const float v = (acc2[m][r] + bb) * gate_s[b];
                ws[(size_t)(e * NB * NT + b * NT + t) * ND + c] = v;
            }
        }
    }
}

// ---------------- reduce 4 expert contributions + finalize aux ---------------
__global__ __launch_bounds__(256)
void moe_reduce(const float* __restrict__ ws,
                const float* __restrict__ aux_partial,
                float* __restrict__ out)
{
    const int i = blockIdx.x * blockDim.x + threadIdx.x;
    const int stride = NB * NT * ND / 4;
    const float4* w = (const float4*)ws;
    const float4 a = w[i];
    const float4 b = w[i + stride];
    const float4 c = w[i + 2 * stride];
    const float4 d = w[i + 3 * stride];
    float4 r;
    r.x = a.x + b.x + c.x + d.x;
    r.y = a.y + b.y + c.y + d.y;
    r.z = a.z + b.z + c.z + d.z;
    r.w = a.w + b.w + c.w + d.w;
    ((float4*)out)[i] = r;

    if (blockIdx.x == 0) {
        const int tid = threadIdx.x;
        float s = aux_partial[tid] + aux_partial[tid + 256];
        #pragma unroll
        for (int off = 32; off > 0; off >>= 1) s += __shfl_xor(s, off);
        __shared__ float wsum[4];
        if ((tid & 63) == 0) wsum[tid >> 6] = s;
        __syncthreads();
        if (tid == 0)
            out[NB * NT * ND] = (wsum[0] + wsum[1] + wsum[2] + wsum[3]) *
                                (0.01f / (NB * NT));
    }
}

// ---------------- fallback (ws too small): self-contained, atomics -----------
__global__ __launch_bounds__(256, 2)
void moe_main_fb(const float* __restrict__ x,
                 const float* __restrict__ w1,
                 const float* __restrict__ b1,
                 const float* __restrict__ w2,
                 const float* __restrict__ b2,
                 const float* __restrict__ rw,
                 const float* __restrict__ rb,
                 float* __restrict__ out)
{
    const int blk  = blockIdx.x;
    const int t    = blk >> 2;
    const int e    = blk & 3;
    const int tid  = threadIdx.x;
    const int lane = tid & 63;
    const int wave = tid >> 6;
    const int l15  = lane & 15;
    const int l4   = lane >> 4;

    __shared__ short Hs[NB][NK + 8];
    __shared__ float gate_s[NB];

    if (tid < NB) {
        const int b = tid;
        const float* xr = x + (b * NT + t) * ND;
        float l0 = rb[0], l1 = rb[1], l2 = rb[2], l3 = rb[3];
        #pragma unroll 8
        for (int d = 0; d < ND; ++d) {
            const float xv = xr[d];
            const float* w = rw + d * NE;
            l0 += xv * w[0]; l1 += xv * w[1]; l2 += xv * w[2]; l3 += xv * w[3];
        }
        l0 = fmaxf(l0, 0.f); l1 = fmaxf(l1, 0.f); l2 = fmaxf(l2, 0.f); l3 = fmaxf(l3, 0.f);
        const float ss  = l0 + l1 + l2 + l3;
        const float inv = 1.f / (ss + 1e-9f);
        const float ge  = (e == 0) ? l0 : (e == 1) ? l1 : (e == 2) ? l2 : l3;
        gate_s[b] = ge * inv;
        if (e == 0) {
            float aux = ss * inv;
            #pragma unroll
            for (int off = 32; off > 0; off >>= 1) aux += __shfl_down(aux, off);
            if (lane == 0) atomicAdd(out + NB * NT * ND, aux * (0.01f / (NB * NT)));
        }
    }
    __syncthreads();

    const float* W1 = w1 + (size_t)((t * NE + e) * ND) * NK;
    const float* B1 = b1 + (t * NE + e) * NK;
    const int n0 = wave * 128;

    f32x4 acc[4][8];
    #pragma unroll
    for (int m = 0; m < 4; ++m)
        #pragma unroll
        for (int n = 0; n < 8; ++n) acc[m][n] = (f32x4){0.f, 0.f, 0.f, 0.f};

    #pragma unroll
    for (int ks = 0; ks < 4; ++ks) {
        const int d0 = ks * 32 + l4 * 8;
        bf16x8 afr[4];
        #pragma unroll
        for (int m = 0; m < 4; ++m) {
            const int b = m * 16 + l15;
            const float* xp = x + (b * NT + t) * ND + d0;
            float xf[8];
            *(float4*)&xf[0] = *(const float4*)(xp);
            *(float4*)&xf[4] = *(const float4*)(xp + 4);
            afr[m] = cvt8(xf);
        }
        #pragma unroll
        for (int nt = 0; nt < 8; ++nt) {
            const int n = n0 + nt * 16 + l15;
            const float* wp = W1 + (size_t)d0 * NK + n;
            float wf[8];
            #pragma unroll
            for (int j = 0; j < 8; ++j) wf[j] = wp[(size_t)j * NK];
            const bf16x8 bfr = cvt8(wf);
            #pragma unroll
            for (int m = 0; m < 4; ++m)
                acc[m][nt] = __builtin_amdgcn_mfma_f32_16x16x32_bf16(afr[m], bfr, acc[m][nt], 0, 0, 0);
        }
    }

    #pragma unroll
    for (int nt = 0; nt < 8; ++nt) {
        const int n = n0 + nt * 16 + l15;
        const float bb = B1[n];
        #pragma unroll
        for (int m = 0; m < 4; ++m) {
            const int row = m * 16 + l4 * 4;
            #pragma unroll
            for (int r = 0; r < 4; ++r) {
                const float hh = acc[m][nt][r] + bb;
                Hs[row + r][n] = f2bf(gelu_erf(hh));
            }
        }
    }
    __syncthreads();

    const float* W2 = w2 + (size_t)((t * NE + e) * NK) * ND;
    const float* B2 = b2 + (t * NE + e) * ND;
    const int c0 = wave * 32;

    f32x4 acc2[4][2];
    #pragma unroll
    for (int m = 0; m < 4; ++m)
        #pragma unroll
        for (int n = 0; n < 2; ++n) acc2[m][n] = (f32x4){0.f, 0.f, 0.f, 0.f};

    #pragma unroll 4
    for (int ks = 0; ks < 16; ++ks) {
        const int k0 = ks * 32 + l4 * 8;
        bf16x8 afr[4];
        #pragma unroll
        for (int m = 0; m < 4; ++m)
            afr[m] = *(const bf16x8*)(&Hs[m * 16 + l15][k0]);
        #pragma unroll
        for (int nt = 0; nt < 2; ++nt) {
            const int c = c0 + nt * 16 + l15;
            const float* wp = W2 + (size_t)k0 * ND + c;
            float wf[8];
            #pragma unroll
            for (int j = 0; j < 8; ++j) wf[j] = wp[(size_t)j * ND];
            const bf16x8 bfr = cvt8(wf);
            #pragma unroll
            for (int m = 0; m < 4; ++m)
                acc2[m][nt] = __builtin_amdgcn_mfma_f32_16x16x32_bf16(afr[m], bfr, acc2[m][nt], 0, 0, 0);
        }
    }

    #pragma unroll
    for (int nt = 0; nt < 2; ++nt) {
        const int c = c0 + nt * 16 + l15;
        const float bb = B2[c];
        #pragma unroll
        for (int m = 0; m < 4; ++m) {
            #pragma unroll
            for (int r = 0; r < 4; ++r) {
                const int b = m * 16 + l4 * 4 + r;
                const float v = (acc2[m][nt][r] + bb) * gate_s[b];
                atomicAdd(out + (size_t)(b * NT + t) * ND + c, v);
            }
        }
    }
}

extern "C" void kernel_launch(void* const* d_in, const int* in_sizes, int n_in,
                              void* d_out, int out_size, void* d_ws, size_t ws_size,
                              hipStream_t stream) {
    const float* x  = (const float*)d_in[0];
    const float* w1 = (const float*)d_in[1];
    const float* b1 = (const float*)d_in[2];
    const float* w2 = (const float*)d_in[3];
    const float* b2 = (const float*)d_in[4];
    const float* rw = (const float*)d_in[5];
    const float* rb = (const float*)d_in[6];
    float* out = (float*)d_out;

    const size_t contrib_elems = (size_t)NE * NB * NT * ND;           // 16 MiB
    const size_t gates_elems   = (size_t)NB * NT * NE;
    const size_t aux_elems     = 512;
    const size_t ws_need = (contrib_elems + gates_elems + aux_elems) * sizeof(float);

    if (ws_size >= ws_need) {
        float* contrib = (float*)d_ws;
        float* gates   = contrib + contrib_elems;
        float* auxp    = gates + gates_elems;

        moe_gates<<<512, 256, 0, stream>>>(x, rw, rb, gates, auxp);
        moe_main<<<NT * NE, 512, 0, stream>>>(x, w1, b1, w2, b2, gates, contrib);
        moe_reduce<<<(NB * NT * ND / 4) / 256, 256, 0, stream>>>(contrib, auxp, out);
    } else {
        hipMemsetAsync(d_out, 0, (size_t)(NB * NT * ND + 1) * sizeof(float), stream);
        moe_main_fb<<<NT * NE, 256, 0, stream>>>(x, w1, b1, w2, b2, rw, rb, out);
    }
}